// Round 7
// baseline (354.035 us; speedup 1.0000x reference)
//
#include <hip/hip_runtime.h>
#include <math.h>

#define NB 4096
#define NT 2048
#define VM 256
#define VT 128
#define NOUT 1158
#define EPSF 1e-9f

// One block (256 threads = 4 waves) per batch row.
// LDS histograms: cnt/sum/sum2 for mcc (256 cats) and tr_type (128 cats).
__global__ __launch_bounds__(256) void agg_feature_kernel(
    const float* __restrict__ amount,
    const int*   __restrict__ mcc,
    const int*   __restrict__ trt,
    const int*   __restrict__ seq_lens,
    float*       __restrict__ out)
{
    const int row = blockIdx.x;
    const int tid = threadIdx.x;

    __shared__ float s_cnt_m[VM], s_sv_m[VM], s_sv2_m[VM];
    __shared__ float s_cnt_t[VT], s_sv_t[VT], s_sv2_t[VT];
    __shared__ float s_part[8];       // 4 waves x {sum, sum2}
    __shared__ float s_distinct[2];

    // zero-init LDS (d_ws/d_out are poisoned 0xAA; LDS is ours to init)
    s_cnt_m[tid] = 0.f; s_sv_m[tid] = 0.f; s_sv2_m[tid] = 0.f;
    if (tid < VT) { s_cnt_t[tid] = 0.f; s_sv_t[tid] = 0.f; s_sv2_t[tid] = 0.f; }
    if (tid < 2)  { s_distinct[tid] = 0.f; }
    __syncthreads();

    const float4* a4 = (const float4*)(amount + (size_t)row * NT);
    const int4*   m4 = (const int4*)(mcc    + (size_t)row * NT);
    const int4*   t4 = (const int4*)(trt    + (size_t)row * NT);

    float lsum = 0.f, lsum2 = 0.f;

    #pragma unroll
    for (int it = 0; it < NT / (256 * 4); ++it) {
        const int i = it * 256 + tid;               // float4 index, coalesced
        const float4 av = a4[i];
        const int4   mv = m4[i];
        const int4   tv = t4[i];

        const float va[4] = {av.x, av.y, av.z, av.w};
        const int   mi[4] = {mv.x, mv.y, mv.z, mv.w};
        const int   ti[4] = {tv.x, tv.y, tv.z, tv.w};

        #pragma unroll
        for (int j = 0; j < 4; ++j) {
            const float a = va[j];
            float v = expm1f(fabsf(a));
            v = copysignf(v, a);                    // sign(0) -> v stays 0
            const float v2 = v * v;
            lsum  += v;
            lsum2 += v2;

            int m = mi[j]; m = m < 0 ? 0 : (m > VM - 1 ? VM - 1 : m);
            int t = ti[j]; t = t < 0 ? 0 : (t > VT - 1 ? VT - 1 : t);

            atomicAdd(&s_cnt_m[m], 1.f);
            atomicAdd(&s_sv_m[m],  v);
            atomicAdd(&s_sv2_m[m], v2);
            atomicAdd(&s_cnt_t[t], 1.f);
            atomicAdd(&s_sv_t[t],  v);
            atomicAdd(&s_sv2_t[t], v2);
        }
    }

    // wave-level reduce of scalar sums (64 lanes)
    #pragma unroll
    for (int off = 32; off > 0; off >>= 1) {
        lsum  += __shfl_down(lsum,  off);
        lsum2 += __shfl_down(lsum2, off);
    }
    const int wave = tid >> 6;
    if ((tid & 63) == 0) { s_part[wave] = lsum; s_part[4 + wave] = lsum2; }

    __syncthreads();   // all LDS atomics + s_part visible

    float tot_sum = 0.f, tot_sum2 = 0.f;
    if (tid == 0) {
        tot_sum  = s_part[0] + s_part[1] + s_part[2] + s_part[3];
        tot_sum2 = s_part[4] + s_part[5] + s_part[6] + s_part[7];
    }

    float* orow = out + (size_t)row * NOUT;

    // ---- mcc categories: tid == category ----
    {
        const float cnt  = s_cnt_m[tid];
        const float ecnt = (tid == 0) ? 0.f : cnt;   // category 0 masked
        const float sv   = s_sv_m[tid];
        const float sv2  = s_sv2_m[tid];
        orow[4 + tid] = ecnt;
        orow[4 + VM + tid] = sv / (ecnt + EPSF);
        float av = sv2 - (sv * sv) / (ecnt + EPSF);
        av = av < 0.f ? 0.f : av;
        float dn = ecnt - 1.f; dn = dn < 0.f ? 0.f : dn;
        orow[4 + 2 * VM + tid] = sqrtf(av / (dn + EPSF));

        const unsigned long long bm = __ballot(ecnt > 0.f);
        if ((tid & 63) == 0) atomicAdd(&s_distinct[0], (float)__popcll(bm));
    }

    // ---- tr_type categories: tid < 128 (waves 0-1 fully active) ----
    if (tid < VT) {
        const float cnt  = s_cnt_t[tid];
        const float ecnt = (tid == 0) ? 0.f : cnt;
        const float sv   = s_sv_t[tid];
        const float sv2  = s_sv2_t[tid];
        const int base = 4 + 3 * VM;
        orow[base + tid] = ecnt;
        orow[base + VT + tid] = sv / (ecnt + EPSF);
        float av = sv2 - (sv * sv) / (ecnt + EPSF);
        av = av < 0.f ? 0.f : av;
        float dn = ecnt - 1.f; dn = dn < 0.f ? 0.f : dn;
        orow[base + 2 * VT + tid] = sqrtf(av / (dn + EPSF));

        const unsigned long long bm = __ballot(ecnt > 0.f);
        if ((tid & 63) == 0) atomicAdd(&s_distinct[1], (float)__popcll(bm));
    }

    __syncthreads();   // distinct counters complete

    if (tid == 0) {
        const float sl = (float)seq_lens[row];
        const float mean = tot_sum / (sl + EPSF);
        float a = tot_sum2 - (tot_sum * tot_sum) / (sl + EPSF);
        a = a < 0.f ? 0.f : a;
        float dn = sl - 1.f; dn = dn < 0.f ? 0.f : dn;
        const float stdv = sqrtf(a / (dn + EPSF));
        orow[0] = sl;
        orow[1] = tot_sum;
        orow[2] = mean;
        orow[3] = stdv;
        orow[4 + 3 * VM + 3 * VT]     = s_distinct[0];
        orow[4 + 3 * VM + 3 * VT + 1] = s_distinct[1];
    }
}

extern "C" void kernel_launch(void* const* d_in, const int* in_sizes, int n_in,
                              void* d_out, int out_size, void* d_ws, size_t ws_size,
                              hipStream_t stream) {
    const float* amount   = (const float*)d_in[0];
    const int*   mcc      = (const int*)d_in[1];
    const int*   trt      = (const int*)d_in[2];
    const int*   seq_lens = (const int*)d_in[3];
    float* out = (float*)d_out;

    agg_feature_kernel<<<NB, 256, 0, stream>>>(amount, mcc, trt, seq_lens, out);
}

// Round 9
// 280.857 us; speedup vs baseline: 1.2606x; 1.2606x over previous
//
#include <hip/hip_runtime.h>
#include <math.h>

#define NB 4096
#define NT 2048
#define VM 256
#define VT 128
#define NOUT 1158
#define EPSF 1e-9f

// Common epilogue math
__device__ __forceinline__ void write_cat(float* orow, int base, int V, int tid,
                                          float cnt, float sv, float sv2,
                                          float* s_distinct, int slot) {
    const float ecnt = (tid == 0) ? 0.f : cnt;   // category 0 masked
    orow[base + tid] = ecnt;
    orow[base + V + tid] = sv / (ecnt + EPSF);
    float av = sv2 - (sv * sv) / (ecnt + EPSF);
    av = av < 0.f ? 0.f : av;
    float dn = ecnt - 1.f; dn = dn < 0.f ? 0.f : dn;
    orow[base + 2 * V + tid] = sqrtf(av / (dn + EPSF));
    const unsigned long long bm = __ballot(ecnt > 0.f);
    if ((tid & 63) == 0) atomicAdd(&s_distinct[slot], (float)__popcll(bm));
}

__device__ __forceinline__ void write_scalars(float* orow, int tid, int row,
                                              const int* seq_lens,
                                              float tot_sum, float tot_sum2,
                                              const float* s_distinct) {
    if (tid == 0) {
        const float sl = (float)seq_lens[row];
        const float mean = tot_sum / (sl + EPSF);
        float a = tot_sum2 - (tot_sum * tot_sum) / (sl + EPSF);
        a = a < 0.f ? 0.f : a;
        float dn = sl - 1.f; dn = dn < 0.f ? 0.f : dn;
        orow[0] = sl;
        orow[1] = tot_sum;
        orow[2] = mean;
        orow[3] = sqrtf(a / (dn + EPSF));
        orow[4 + 3 * VM + 3 * VT]     = s_distinct[0];
        orow[4 + 3 * VM + 3 * VT + 1] = s_distinct[1];
    }
}

// ---------------- Variant A: 6x f32 LDS atomics (baseline) ----------------
__global__ __launch_bounds__(256) void agg_feature_a(
    const float* __restrict__ amount, const int* __restrict__ mcc,
    const int* __restrict__ trt, const int* __restrict__ seq_lens,
    float* __restrict__ out)
{
    const int row = blockIdx.x;               // rows [0, NB/2)
    const int tid = threadIdx.x;

    __shared__ float s_cnt_m[VM], s_sv_m[VM], s_sv2_m[VM];
    __shared__ float s_cnt_t[VT], s_sv_t[VT], s_sv2_t[VT];
    __shared__ float s_part[8];
    __shared__ float s_distinct[2];

    s_cnt_m[tid] = 0.f; s_sv_m[tid] = 0.f; s_sv2_m[tid] = 0.f;
    if (tid < VT) { s_cnt_t[tid] = 0.f; s_sv_t[tid] = 0.f; s_sv2_t[tid] = 0.f; }
    if (tid < 2)  { s_distinct[tid] = 0.f; }
    __syncthreads();

    const float4* a4 = (const float4*)(amount + (size_t)row * NT);
    const int4*   m4 = (const int4*)(mcc    + (size_t)row * NT);
    const int4*   t4 = (const int4*)(trt    + (size_t)row * NT);

    float lsum = 0.f, lsum2 = 0.f;
    #pragma unroll
    for (int it = 0; it < NT / (256 * 4); ++it) {
        const int i = it * 256 + tid;
        const float4 av = a4[i];
        const int4   mv = m4[i];
        const int4   tv = t4[i];
        const float va[4] = {av.x, av.y, av.z, av.w};
        const int   mi[4] = {mv.x, mv.y, mv.z, mv.w};
        const int   ti[4] = {tv.x, tv.y, tv.z, tv.w};
        #pragma unroll
        for (int j = 0; j < 4; ++j) {
            const float a = va[j];
            float v = copysignf(expm1f(fabsf(a)), a);
            const float v2 = v * v;
            lsum += v; lsum2 += v2;
            int m = mi[j]; m = m < 0 ? 0 : (m > VM - 1 ? VM - 1 : m);
            int t = ti[j]; t = t < 0 ? 0 : (t > VT - 1 ? VT - 1 : t);
            atomicAdd(&s_cnt_m[m], 1.f);
            atomicAdd(&s_sv_m[m],  v);
            atomicAdd(&s_sv2_m[m], v2);
            atomicAdd(&s_cnt_t[t], 1.f);
            atomicAdd(&s_sv_t[t],  v);
            atomicAdd(&s_sv2_t[t], v2);
        }
    }

    #pragma unroll
    for (int off = 32; off > 0; off >>= 1) {
        lsum  += __shfl_down(lsum,  off);
        lsum2 += __shfl_down(lsum2, off);
    }
    const int wave = tid >> 6;
    if ((tid & 63) == 0) { s_part[wave] = lsum; s_part[4 + wave] = lsum2; }
    __syncthreads();

    float tot_sum = 0.f, tot_sum2 = 0.f;
    if (tid == 0) {
        tot_sum  = s_part[0] + s_part[1] + s_part[2] + s_part[3];
        tot_sum2 = s_part[4] + s_part[5] + s_part[6] + s_part[7];
    }

    float* orow = out + (size_t)row * NOUT;
    write_cat(orow, 4, VM, tid, s_cnt_m[tid], s_sv_m[tid], s_sv2_m[tid], s_distinct, 0);
    if (tid < VT)
        write_cat(orow, 4 + 3 * VM, VT, tid, s_cnt_t[tid], s_sv_t[tid], s_sv2_t[tid], s_distinct, 1);
    __syncthreads();
    write_scalars(orow, tid, row, seq_lens, tot_sum, tot_sum2, s_distinct);
}

// ---------------- Variant B: packed u64 (cnt|sv) + f32 sv2 = 4 atomics ----------------
// pk = (cnt << 48) | sum_fixed, where each term adds ((v + 1024) * 2^16).
// Max low field: 2048 * (1450 * 65536) ~ 1.9e11 < 2^48. De-bias: sv = (lo - cnt*1024*2^16) / 2^16.
__global__ __launch_bounds__(256) void agg_feature_b(
    const float* __restrict__ amount, const int* __restrict__ mcc,
    const int* __restrict__ trt, const int* __restrict__ seq_lens,
    float* __restrict__ out)
{
    const int row = blockIdx.x + NB / 2;      // rows [NB/2, NB)
    const int tid = threadIdx.x;

    __shared__ unsigned long long s_pk_m[VM];
    __shared__ float s_sv2_m[VM];
    __shared__ unsigned long long s_pk_t[VT];
    __shared__ float s_sv2_t[VT];
    __shared__ float s_part[8];
    __shared__ float s_distinct[2];

    s_pk_m[tid] = 0ULL; s_sv2_m[tid] = 0.f;
    if (tid < VT) { s_pk_t[tid] = 0ULL; s_sv2_t[tid] = 0.f; }
    if (tid < 2)  { s_distinct[tid] = 0.f; }
    __syncthreads();

    const float4* a4 = (const float4*)(amount + (size_t)row * NT);
    const int4*   m4 = (const int4*)(mcc    + (size_t)row * NT);
    const int4*   t4 = (const int4*)(trt    + (size_t)row * NT);

    float lsum = 0.f, lsum2 = 0.f;
    #pragma unroll
    for (int it = 0; it < NT / (256 * 4); ++it) {
        const int i = it * 256 + tid;
        const float4 av = a4[i];
        const int4   mv = m4[i];
        const int4   tv = t4[i];
        const float va[4] = {av.x, av.y, av.z, av.w};
        const int   mi[4] = {mv.x, mv.y, mv.z, mv.w};
        const int   ti[4] = {tv.x, tv.y, tv.z, tv.w};
        #pragma unroll
        for (int j = 0; j < 4; ++j) {
            const float a = va[j];
            float v = copysignf(expm1f(fabsf(a)), a);
            const float v2 = v * v;
            lsum += v; lsum2 += v2;
            int m = mi[j]; m = m < 0 ? 0 : (m > VM - 1 ? VM - 1 : m);
            int t = ti[j]; t = t < 0 ? 0 : (t > VT - 1 ? VT - 1 : t);

            const unsigned fixed = (unsigned)((v + 1024.0f) * 65536.0f);
            const unsigned long long pk = (1ULL << 48) | (unsigned long long)fixed;
            atomicAdd(&s_pk_m[m], pk);
            atomicAdd(&s_sv2_m[m], v2);
            atomicAdd(&s_pk_t[t], pk);
            atomicAdd(&s_sv2_t[t], v2);
        }
    }

    #pragma unroll
    for (int off = 32; off > 0; off >>= 1) {
        lsum  += __shfl_down(lsum,  off);
        lsum2 += __shfl_down(lsum2, off);
    }
    const int wave = tid >> 6;
    if ((tid & 63) == 0) { s_part[wave] = lsum; s_part[4 + wave] = lsum2; }
    __syncthreads();

    float tot_sum = 0.f, tot_sum2 = 0.f;
    if (tid == 0) {
        tot_sum  = s_part[0] + s_part[1] + s_part[2] + s_part[3];
        tot_sum2 = s_part[4] + s_part[5] + s_part[6] + s_part[7];
    }

    float* orow = out + (size_t)row * NOUT;
    {
        const unsigned long long p = s_pk_m[tid];
        const unsigned cnt_u = (unsigned)(p >> 48);
        const long long net = (long long)(p & 0xFFFFFFFFFFFFULL)
                            - (long long)cnt_u * (1024LL << 16);
        const float sv = (float)net * (1.0f / 65536.0f);
        write_cat(orow, 4, VM, tid, (float)cnt_u, sv, s_sv2_m[tid], s_distinct, 0);
    }
    if (tid < VT) {
        const unsigned long long p = s_pk_t[tid];
        const unsigned cnt_u = (unsigned)(p >> 48);
        const long long net = (long long)(p & 0xFFFFFFFFFFFFULL)
                            - (long long)cnt_u * (1024LL << 16);
        const float sv = (float)net * (1.0f / 65536.0f);
        write_cat(orow, 4 + 3 * VM, VT, tid, (float)cnt_u, sv, s_sv2_t[tid], s_distinct, 1);
    }
    __syncthreads();
    write_scalars(orow, tid, row, seq_lens, tot_sum, tot_sum2, s_distinct);
}

extern "C" void kernel_launch(void* const* d_in, const int* in_sizes, int n_in,
                              void* d_out, int out_size, void* d_ws, size_t ws_size,
                              hipStream_t stream) {
    const float* amount   = (const float*)d_in[0];
    const int*   mcc      = (const int*)d_in[1];
    const int*   trt      = (const int*)d_in[2];
    const int*   seq_lens = (const int*)d_in[3];
    float* out = (float*)d_out;

    agg_feature_a<<<NB / 2, 256, 0, stream>>>(amount, mcc, trt, seq_lens, out);
    agg_feature_b<<<NB / 2, 256, 0, stream>>>(amount, mcc, trt, seq_lens, out);
}